// Round 1
// baseline (362.831 us; speedup 1.0000x reference)
//
#include <hip/hip_runtime.h>
#include <stdint.h>

#define NN 4096
#define NC 7
#define SIG1 0.7310585786300049f
#define PER_C 0.001f

// ---------------- ws layout ----------------
// [0, 2MB)        : uint64 bits[4096][64]   bitset of adj rows
// [2MB, +16KB)    : int    deg[4096]
// [+16KB, +16KB)  : float  diagP[4096]
// then floats     : T[49], ce_sum, Ncnt[7](int), masks[4](uint)
#define BITS_OFF   0
#define DEG_OFF    (2*1024*1024)
#define DIAGP_OFF  (DEG_OFF + NN*4)
#define ACC_OFF    (DIAGP_OFF + NN*4)
// ACC region word indices: 0..48 = T, 49 = ce_sum, 50..56 = Ncnt, 57..60 = masks
#define ACC_WORDS  61

__global__ void k_zero(float* acc) {
    int t = threadIdx.x;
    if (t < ACC_WORDS) acc[t] = 0.0f;  // zeroes float T/ce and int Ncnt/masks (bit pattern 0)
}

// Build bitset: one wave builds one u64 word via ballot over 64 consecutive adj ints.
__global__ void k_build_bits(const int* __restrict__ adj, unsigned long long* __restrict__ bits) {
    long long wid = ((long long)blockIdx.x * blockDim.x + threadIdx.x) >> 6; // word index 0..262143
    int lane = threadIdx.x & 63;
    int elem = adj[wid * 64 + lane];
    unsigned long long m = __ballot(elem != 0);
    if (lane == 0) bits[wid] = m;
}

// Per-node prep: deg, diagP, Ncnt, ce partial sum.
__global__ void k_prep(const float* __restrict__ preds, const int* __restrict__ labels,
                       const int* __restrict__ mask, const unsigned long long* __restrict__ bits,
                       int* __restrict__ deg, float* __restrict__ diagP,
                       float* __restrict__ ce_sum, int* __restrict__ Ncnt) {
    int p = blockIdx.x * blockDim.x + threadIdx.x;  // 4096 threads
    const unsigned long long* row = bits + (size_t)p * 64;
    int d = 0;
    #pragma unroll
    for (int w = 0; w < 64; w++) d += __popcll(row[w]);
    deg[p] = d;

    int l = labels[p];
    const float* pr = preds + p * NC;
    float x[NC];
    #pragma unroll
    for (int c = 0; c < NC; c++) x[c] = pr[c];
    float mx = x[0];
    #pragma unroll
    for (int c = 1; c < NC; c++) mx = fmaxf(mx, x[c]);
    float s = 0.f;
    #pragma unroll
    for (int c = 0; c < NC; c++) s += __expf(x[c] - mx);
    float lse = mx + logf(s);
    float dp = x[l];
    diagP[p] = dp;
    if (mask[p]) atomicAdd(&Ncnt[l], 1);

    // block-reduce ce contribution, one global atomic per block
    __shared__ float red[256];
    red[threadIdx.x] = lse - dp;
    __syncthreads();
    for (int st = 128; st > 0; st >>= 1) {
        if (threadIdx.x < st) red[threadIdx.x] += red[threadIdx.x + st];
        __syncthreads();
    }
    if (threadIdx.x == 0) atomicAdd(ce_sum, red[0]);
}

// Pair kernel: 64x64 pair tile per block, 4x4 pairs per thread, bitset popcount Gram.
#define BP 64
#define BQ 64
__launch_bounds__(256, 2)
__global__ void k_pairs(const unsigned long long* __restrict__ bits,
                        const float* __restrict__ preds,
                        const int* __restrict__ labels,
                        const int* __restrict__ mask,
                        const int* __restrict__ deg,
                        const float* __restrict__ diagP,
                        float* __restrict__ T,
                        unsigned int* __restrict__ g_masks) {
    __shared__ unsigned long long lp_bits[BP * 65];   // padded: p-reads conflict-free
    __shared__ unsigned long long lq_bits[BQ * 65];   // word-rotated by (row>>2): q-reads conflict-free
    __shared__ float predsQ[BQ * 8];
    __shared__ float diagPp[BP];
    __shared__ int labP[BP], labQ[BQ], mP[BP], mQ[BQ], degP[BP];
    __shared__ float T_lds[49];
    __shared__ unsigned int s_m[4];  // sub_lo, sub_hi, inter_lo, inter_hi

    int t = threadIdx.x;
    int p0 = blockIdx.y * BP, q0 = blockIdx.x * BQ;

    if (t < 49) T_lds[t] = 0.f;
    if (t >= 49 && t < 53) s_m[t - 49] = 0u;

    #pragma unroll
    for (int i = 0; i < 16; i++) {
        int idx = t + 256 * i;            // 0..4095
        int row = idx >> 6, w = idx & 63;
        lp_bits[row * 65 + w] = bits[(size_t)(p0 + row) * 64 + w];
        lq_bits[row * 65 + ((w + (row >> 2)) & 63)] = bits[(size_t)(q0 + row) * 64 + w];
    }
    for (int idx = t; idx < BQ * NC; idx += 256) {
        int r = idx / NC, c = idx - r * NC;
        predsQ[r * 8 + c] = preds[(q0 + r) * NC + c];
    }
    if (t < 64) {
        diagPp[t] = diagP[p0 + t];
        labP[t] = labels[p0 + t];
        labQ[t] = labels[q0 + t];
        mP[t] = mask[p0 + t];
        mQ[t] = mask[q0 + t];
        degP[t] = deg[p0 + t];
    }
    __syncthreads();

    int tx = t & 15, ty = t >> 4;       // 16x16 thread grid; wave = 4 consecutive ty values
    int cnt[4][4] = {};
    #pragma unroll 4
    for (int w = 0; w < 64; w++) {
        unsigned long long a[4], b[4];
        #pragma unroll
        for (int i = 0; i < 4; i++) a[i] = lp_bits[(4 * ty + i) * 65 + w];
        #pragma unroll
        for (int j = 0; j < 4; j++) b[j] = lq_bits[(4 * tx + j) * 65 + ((w + tx) & 63)];
        #pragma unroll
        for (int i = 0; i < 4; i++)
            #pragma unroll
            for (int j = 0; j < 4; j++)
                cnt[i][j] += __popcll(a[i] & b[j]);
    }

    unsigned long long lsub = 0ull, linter = 0ull;
    #pragma unroll
    for (int i = 0; i < 4; i++) {
        int pl = 4 * ty + i;
        int lp = labP[pl], mp = mP[pl], dgp = degP[pl];
        float dPp = diagPp[pl];
        #pragma unroll
        for (int j = 0; j < 4; j++) {
            int ql = 4 * tx + j;
            int q = q0 + ql;
            int inter = cnt[i][j];
            int qw = q >> 6, qb = q & 63;
            int bit_pq = (int)((lp_bits[pl * 65 + qw] >> qb) & 1ull);               // adj[p,q]
            int bit_qq = (int)((lq_bits[ql * 65 + ((qw + tx) & 63)] >> qb) & 1ull); // adj[q,q]
            int sub = dgp - (inter + (bit_pq & (bit_qq ^ 1)));
            int lq = labQ[ql];
            if (mp && mQ[ql]) {
                int bidx = lp * 7 + lq;
                if (sub > 0)   lsub   |= 1ull << bidx;
                if (inter > 0) linter |= 1ull << bidx;
                if (lp != lq) {
                    float arg = (1.f + SIG1 * (float)sub) / (1.f + SIG1 * (float)inter);
                    float v = 1.f / (1.f + __expf(arg));          // 1 - sigmoid(arg)
                    float E = __expf(predsQ[ql * 8 + lp] - dPp);  // exp(G - diagP)
                    atomicAdd(&T_lds[bidx], E * v);
                }
            }
        }
    }
    atomicOr(&s_m[0], (unsigned int)(lsub & 0xffffffffull));
    atomicOr(&s_m[1], (unsigned int)(lsub >> 32));
    atomicOr(&s_m[2], (unsigned int)(linter & 0xffffffffull));
    atomicOr(&s_m[3], (unsigned int)(linter >> 32));
    __syncthreads();

    if (t < 49) { float v = T_lds[t]; if (v != 0.f) atomicAdd(&T[t], v); }
    if (t >= 64 && t < 68) { unsigned int m = s_m[t - 64]; if (m) atomicOr(&g_masks[t - 64], m); }
}

__global__ void k_final(const float* __restrict__ acc, float* __restrict__ out) {
    if (threadIdx.x == 0 && blockIdx.x == 0) {
        const float* T = acc;
        float ce_sum = acc[49];
        const int* Ncnt = (const int*)(acc + 50);
        const unsigned int* m = (const unsigned int*)(acc + 57);
        unsigned long long sub  = (unsigned long long)m[0] | ((unsigned long long)m[1] << 32);
        unsigned long long intr = (unsigned long long)m[2] | ((unsigned long long)m[3] << 32);
        unsigned long long hb = sub & intr;
        float invN[NC];
        #pragma unroll
        for (int c = 0; c < NC; c++) { int n = Ncnt[c]; invN[c] = (n > 0) ? 1.f / (float)n : 0.f; }
        float lp = 0.f;
        for (int c1 = 0; c1 < NC; c1++)
            for (int c2 = 0; c2 < NC; c2++) {
                int b = c1 * 7 + c2;
                if ((hb >> b) & 1ull) lp += invN[c1] * invN[c2] * T[b];
            }
        out[0] = ce_sum / (float)NN + PER_C * lp;
    }
}

extern "C" void kernel_launch(void* const* d_in, const int* in_sizes, int n_in,
                              void* d_out, int out_size, void* d_ws, size_t ws_size,
                              hipStream_t stream) {
    const float* preds  = (const float*)d_in[0];
    const int*   labels = (const int*)d_in[1];
    const int*   mask   = (const int*)d_in[2];
    const int*   adj    = (const int*)d_in[3];
    float* out = (float*)d_out;

    char* ws = (char*)d_ws;
    unsigned long long* bits = (unsigned long long*)(ws + BITS_OFF);
    int*   deg   = (int*)(ws + DEG_OFF);
    float* diagP = (float*)(ws + DIAGP_OFF);
    float* acc   = (float*)(ws + ACC_OFF);
    float* T      = acc;
    float* ce_sum = acc + 49;
    int*   Ncnt   = (int*)(acc + 50);
    unsigned int* g_masks = (unsigned int*)(acc + 57);

    k_zero<<<1, 64, 0, stream>>>(acc);
    // 4096 rows * 64 words = 262144 waves; 4 waves per 256-thread block
    k_build_bits<<<65536, 256, 0, stream>>>(adj, bits);
    k_prep<<<16, 256, 0, stream>>>(preds, labels, mask, bits, deg, diagP, ce_sum, Ncnt);
    dim3 grid(NN / BQ, NN / BP);
    k_pairs<<<grid, 256, 0, stream>>>(bits, preds, labels, mask, deg, diagP, T, g_masks);
    k_final<<<1, 64, 0, stream>>>(acc, out);
}

// Round 2
// 194.766 us; speedup vs baseline: 1.8629x; 1.8629x over previous
//
#include <hip/hip_runtime.h>
#include <stdint.h>

#define NN 4096
#define NC 7
#define SIG1 0.7310585786300049f
#define PER_C 0.001f

// ---------------- ws layout ----------------
#define BITS_OFF   0                          // u64 bits[4096][64] = 2MB
#define DEG_OFF    (2*1024*1024)              // int deg[4096]
#define DIAGP_OFF  (DEG_OFF   + NN*4)         // float diagP[4096]
#define MIDX_OFF   (DIAGP_OFF + NN*4)         // int midx[4096] (compacted masked node ids, 0-padded)
#define MLAB_OFF   (MIDX_OFF  + NN*4)         // int mlab[4096]
#define ACC_OFF    (MLAB_OFF  + NN*4)
// acc word indices: 0..48 T, 49 ce_sum, 50..56 Ncnt(int), 57..60 masks(uint), 61 M(int)
#define ACC_WORDS  62

// Build bitset rows of adj. 2048 blocks x 256: each wave builds 32 words,
// accumulates them into per-lane registers, one coalesced 256B store per wave.
__global__ void k_build_bits(const int* __restrict__ adj, unsigned long long* __restrict__ bits) {
    int wv = (blockIdx.x * 256 + threadIdx.x) >> 6;   // global wave id, 0..8191
    int lane = threadIdx.x & 63;
    long long w0 = (long long)wv * 32;
    unsigned long long myw = 0ull;
    #pragma unroll 4
    for (int r = 0; r < 32; r++) {
        int elem = adj[(w0 + r) * 64 + lane];
        unsigned long long m = __ballot(elem != 0);
        if (lane == r) myw = m;
    }
    if (lane < 32) bits[w0 + lane] = myw;
}

// Single block: zero accumulators, compact masked nodes (deterministic scan), Ncnt, M.
__global__ void k_compact(const int* __restrict__ labels, const int* __restrict__ mask,
                          int* __restrict__ midx, int* __restrict__ mlab,
                          float* __restrict__ acc) {
    __shared__ int cnts[256];
    __shared__ int sN[NC];
    int t = threadIdx.x;
    if (t < ACC_WORDS) acc[t] = 0.0f;
    if (t < NC) sN[t] = 0;
    for (int i = t; i < NN; i += 256) { midx[i] = 0; mlab[i] = 0; }

    int base_n = t * 16;
    int my[16];
    int c = 0;
    #pragma unroll
    for (int k = 0; k < 16; k++) { my[k] = mask[base_n + k]; c += (my[k] != 0); }
    cnts[t] = c;
    __syncthreads();
    for (int s = 1; s < 256; s <<= 1) {
        int v = (t >= s) ? cnts[t - s] : 0;
        __syncthreads();
        cnts[t] += v;
        __syncthreads();
    }
    int pos = cnts[t] - c;  // exclusive prefix
    #pragma unroll
    for (int k = 0; k < 16; k++) {
        if (my[k]) {
            int node = base_n + k;
            int l = labels[node];
            midx[pos] = node;
            mlab[pos] = l;
            atomicAdd(&sN[l], 1);
            pos++;
        }
    }
    __syncthreads();
    if (t < NC) ((int*)acc)[50 + t] = sN[t];
    if (t == 255) ((int*)acc)[61] = cnts[255];  // M
}

// Per-node (ALL nodes): deg, diagP, ce partial sum.
__global__ void k_prep(const float* __restrict__ preds, const int* __restrict__ labels,
                       const unsigned long long* __restrict__ bits,
                       int* __restrict__ deg, float* __restrict__ diagP,
                       float* __restrict__ ce_sum) {
    int p = blockIdx.x * blockDim.x + threadIdx.x;
    const unsigned long long* row = bits + (size_t)p * 64;
    int d = 0;
    #pragma unroll
    for (int w = 0; w < 64; w++) d += __popcll(row[w]);
    deg[p] = d;

    int l = labels[p];
    const float* pr = preds + p * NC;
    float x[NC];
    #pragma unroll
    for (int c = 0; c < NC; c++) x[c] = pr[c];
    float mx = x[0];
    #pragma unroll
    for (int c = 1; c < NC; c++) mx = fmaxf(mx, x[c]);
    float s = 0.f;
    #pragma unroll
    for (int c = 0; c < NC; c++) s += __expf(x[c] - mx);
    float lse = mx + logf(s);
    float dp = x[l];
    diagP[p] = dp;

    __shared__ float red[256];
    red[threadIdx.x] = lse - dp;
    __syncthreads();
    for (int st = 128; st > 0; st >>= 1) {
        if (threadIdx.x < st) red[threadIdx.x] += red[threadIdx.x + st];
        __syncthreads();
    }
    if (threadIdx.x == 0) atomicAdd(ce_sum, red[0]);
}

// Pair kernel over COMPACTED masked nodes. 64x64 tile, 4x4 per thread.
// LDS tiles stored as 16B chunks (2 u64) at swizzled chunk position c ^ (row>>2):
//  - p-reads (4 distinct ty rows/wave): 4 addrs on 4 bank-groups -> conflict-free
//  - q-reads (16 distinct tx rows/wave): 16 addrs on 8 bank-groups -> 2-way (free)
__launch_bounds__(256, 2)
__global__ void k_pairs(const unsigned long long* __restrict__ bits,
                        const float* __restrict__ preds,
                        const int* __restrict__ deg,
                        const float* __restrict__ diagP,
                        const int* __restrict__ midx,
                        const int* __restrict__ mlab,
                        const int* __restrict__ Mptr,
                        float* __restrict__ T,
                        unsigned int* __restrict__ g_masks) {
    __shared__ ulonglong2 lp[64 * 32];
    __shared__ ulonglong2 lq[64 * 32];
    __shared__ float predsQ[64 * 8];
    __shared__ float diagPp[64];
    __shared__ int labP[64], labQ[64], degP[64], origQ[64];
    __shared__ float T_lds[49];
    __shared__ unsigned int s_m[4];

    int M = *Mptr;
    int p0 = blockIdx.y * 64, q0 = blockIdx.x * 64;
    if (p0 >= M || q0 >= M) return;

    int t = threadIdx.x;
    if (t < 49) T_lds[t] = 0.f;
    if (t >= 49 && t < 53) s_m[t - 49] = 0u;

    #pragma unroll
    for (int i = 0; i < 8; i++) {
        int idx = t + 256 * i;             // 0..2047 chunk slots per tile
        int row = idx >> 5, c = idx & 31;
        int sc = c ^ (row >> 2);
        int pr = midx[p0 + row];
        int qr = midx[q0 + row];
        lp[row * 32 + sc] = *(const ulonglong2*)&bits[(size_t)pr * 64 + 2 * c];
        lq[row * 32 + sc] = *(const ulonglong2*)&bits[(size_t)qr * 64 + 2 * c];
    }
    for (int idx = t; idx < 64 * NC; idx += 256) {
        int r = idx / NC, c = idx - r * NC;
        predsQ[r * 8 + c] = preds[midx[q0 + r] * NC + c];
    }
    if (t < 64) {
        int pi = midx[p0 + t];
        diagPp[t] = diagP[pi];
        degP[t] = deg[pi];
        labP[t] = mlab[p0 + t];
        labQ[t] = mlab[q0 + t];
        origQ[t] = midx[q0 + t];
    }
    __syncthreads();

    int tx = t & 15, ty = t >> 4;
    const ulonglong2* Ap = lp + ty * 128;  // row (4ty+i) chunk base = ty*128 + i*32
    const ulonglong2* Bp = lq + tx * 128;

    int cnt[4][4] = {};
    #pragma unroll 4
    for (int c = 0; c < 32; c++) {
        int sa = c ^ ty, sb = c ^ tx;
        ulonglong2 a[4], b[4];
        #pragma unroll
        for (int i = 0; i < 4; i++) a[i] = Ap[i * 32 + sa];
        #pragma unroll
        for (int j = 0; j < 4; j++) b[j] = Bp[j * 32 + sb];
        #pragma unroll
        for (int i = 0; i < 4; i++)
            #pragma unroll
            for (int j = 0; j < 4; j++)
                cnt[i][j] += __popcll(a[i].x & b[j].x) + __popcll(a[i].y & b[j].y);
    }

    unsigned long long lsub = 0ull, linter = 0ull;
    #pragma unroll
    for (int i = 0; i < 4; i++) {
        int pl = 4 * ty + i;
        bool pOK = (p0 + pl) < M;
        int lp_ = labP[pl], dgp = degP[pl];
        float dPp = diagPp[pl];
        #pragma unroll
        for (int j = 0; j < 4; j++) {
            int ql = 4 * tx + j;
            if (!(pOK && (q0 + ql) < M)) continue;
            int qorig = origQ[ql];
            int qc = qorig >> 7;          // 16B chunk containing bit qorig
            int qh = (qorig >> 6) & 1;    // which u64 half
            ulonglong2 cp = lp[pl * 32 + (qc ^ ty)];
            ulonglong2 cq = lq[ql * 32 + (qc ^ tx)];
            unsigned long long wp = qh ? cp.y : cp.x;
            unsigned long long wq = qh ? cq.y : cq.x;
            int bit_pq = (int)((wp >> (qorig & 63)) & 1ull);   // adj[p,q]
            int bit_qq = (int)((wq >> (qorig & 63)) & 1ull);   // adj[q,q]
            int inter = cnt[i][j];
            int sub = dgp - (inter + (bit_pq & (bit_qq ^ 1)));
            int lq_ = labQ[ql];
            int bidx = lp_ * 7 + lq_;
            if (sub > 0)   lsub   |= 1ull << bidx;
            if (inter > 0) linter |= 1ull << bidx;
            if (lp_ != lq_) {
                float arg = (1.f + SIG1 * (float)sub) / (1.f + SIG1 * (float)inter);
                float v = 1.f / (1.f + __expf(arg));           // 1 - sigmoid(arg)
                float E = __expf(predsQ[ql * 8 + lp_] - dPp);  // exp(G - diagP)
                atomicAdd(&T_lds[bidx], E * v);
            }
        }
    }
    atomicOr(&s_m[0], (unsigned int)(lsub & 0xffffffffull));
    atomicOr(&s_m[1], (unsigned int)(lsub >> 32));
    atomicOr(&s_m[2], (unsigned int)(linter & 0xffffffffull));
    atomicOr(&s_m[3], (unsigned int)(linter >> 32));
    __syncthreads();

    if (t < 49) { float v = T_lds[t]; if (v != 0.f) atomicAdd(&T[t], v); }
    if (t >= 64 && t < 68) { unsigned int m = s_m[t - 64]; if (m) atomicOr(&g_masks[t - 64], m); }
}

__global__ void k_final(const float* __restrict__ acc, float* __restrict__ out) {
    if (threadIdx.x == 0 && blockIdx.x == 0) {
        const float* T = acc;
        float ce_sum = acc[49];
        const int* Ncnt = (const int*)(acc + 50);
        const unsigned int* m = (const unsigned int*)(acc + 57);
        unsigned long long sub  = (unsigned long long)m[0] | ((unsigned long long)m[1] << 32);
        unsigned long long intr = (unsigned long long)m[2] | ((unsigned long long)m[3] << 32);
        unsigned long long hb = sub & intr;
        float invN[NC];
        #pragma unroll
        for (int c = 0; c < NC; c++) { int n = Ncnt[c]; invN[c] = (n > 0) ? 1.f / (float)n : 0.f; }
        float lp = 0.f;
        for (int c1 = 0; c1 < NC; c1++)
            for (int c2 = 0; c2 < NC; c2++) {
                int b = c1 * 7 + c2;
                if ((hb >> b) & 1ull) lp += invN[c1] * invN[c2] * T[b];
            }
        out[0] = ce_sum / (float)NN + PER_C * lp;
    }
}

extern "C" void kernel_launch(void* const* d_in, const int* in_sizes, int n_in,
                              void* d_out, int out_size, void* d_ws, size_t ws_size,
                              hipStream_t stream) {
    const float* preds  = (const float*)d_in[0];
    const int*   labels = (const int*)d_in[1];
    const int*   mask   = (const int*)d_in[2];
    const int*   adj    = (const int*)d_in[3];
    float* out = (float*)d_out;

    char* ws = (char*)d_ws;
    unsigned long long* bits = (unsigned long long*)(ws + BITS_OFF);
    int*   deg   = (int*)(ws + DEG_OFF);
    float* diagP = (float*)(ws + DIAGP_OFF);
    int*   midx  = (int*)(ws + MIDX_OFF);
    int*   mlab  = (int*)(ws + MLAB_OFF);
    float* acc   = (float*)(ws + ACC_OFF);
    float* T      = acc;
    float* ce_sum = acc + 49;
    unsigned int* g_masks = (unsigned int*)(acc + 57);
    int*   Mptr   = (int*)(acc + 61);

    k_build_bits<<<2048, 256, 0, stream>>>(adj, bits);
    k_compact<<<1, 256, 0, stream>>>(labels, mask, midx, mlab, acc);
    k_prep<<<16, 256, 0, stream>>>(preds, labels, bits, deg, diagP, ce_sum);
    dim3 grid(64, 64);
    k_pairs<<<grid, 256, 0, stream>>>(bits, preds, deg, diagP, midx, mlab, Mptr, T, g_masks);
    k_final<<<1, 64, 0, stream>>>(acc, out);
}

// Round 3
// 176.349 us; speedup vs baseline: 2.0575x; 1.1044x over previous
//
#include <hip/hip_runtime.h>
#include <stdint.h>

#define NN 4096
#define NC 7
#define SIG1 0.7310585786300049f
#define PER_C 0.001f

// ---------------- ws layout ----------------
#define BITS_OFF   0                          // u64 bits[4096][64] = 2MB
#define DEG_OFF    (2*1024*1024)              // int deg[4096]
#define DIAGP_OFF  (DEG_OFF   + NN*4)         // float diagP[4096]
#define SELF_OFF   (DIAGP_OFF + NN*4)         // int selfq[4096] = adj[q,q]
#define MIDX_OFF   (SELF_OFF  + NN*4)         // int midx[4096] (compacted masked ids)
#define MLAB_OFF   (MIDX_OFF  + NN*4)         // int mlab[4096]
#define ACC_OFF    (MLAB_OFF  + NN*4)
// acc float-word indices: 0..48 T, 49..55 Ncnt(int), 56..59 masks(uint),
//                         60 M(int), 61..76 ce_part[16]

// Build bitset rows + deg + selfq. One wave per row; 1024 blocks x 256.
__global__ void k_build(const int* __restrict__ adj, unsigned long long* __restrict__ bits,
                        int* __restrict__ deg, int* __restrict__ selfq) {
    int row = blockIdx.x * 4 + (threadIdx.x >> 6);
    int lane = threadIdx.x & 63;
    const int* arow = adj + (size_t)row * NN;
    unsigned long long myw = 0ull;
    #pragma unroll 8
    for (int w = 0; w < 64; w++) {
        unsigned long long m = __ballot(arow[w * 64 + lane] != 0);
        if (lane == w) myw = m;
    }
    bits[(size_t)row * 64 + lane] = myw;
    int d = __popcll(myw);
    #pragma unroll
    for (int o = 32; o > 0; o >>= 1) d += __shfl_down(d, o);
    if (lane == 0) deg[row] = d;
    if (lane == (row >> 6)) selfq[row] = (int)((myw >> (row & 63)) & 1ull);
}

// Blocks 0..15: CE partials + diagP.  Block 16: zero acc, compact scan, Ncnt, M.
__global__ void k_prep2(const float* __restrict__ preds, const int* __restrict__ labels,
                        const int* __restrict__ mask, float* __restrict__ diagP,
                        int* __restrict__ midx, int* __restrict__ mlab,
                        float* __restrict__ acc) {
    int t = threadIdx.x;
    if (blockIdx.x == 16) {
        __shared__ int cnts[256];
        __shared__ int sN[NC];
        if (t < 49) acc[t] = 0.f;                 // T
        if (t >= 56 && t < 60) acc[t] = 0.f;      // masks
        if (t < NC) sN[t] = 0;
        for (int i = t; i < NN; i += 256) { midx[i] = 0; mlab[i] = 0; }

        int base_n = t * 16;
        int my[16];
        int c = 0;
        #pragma unroll
        for (int k = 0; k < 16; k++) { my[k] = mask[base_n + k]; c += (my[k] != 0); }
        cnts[t] = c;
        __syncthreads();
        for (int s = 1; s < 256; s <<= 1) {
            int v = (t >= s) ? cnts[t - s] : 0;
            __syncthreads();
            cnts[t] += v;
            __syncthreads();
        }
        int pos = cnts[t] - c;  // exclusive prefix
        #pragma unroll
        for (int k = 0; k < 16; k++) {
            if (my[k]) {
                int node = base_n + k;
                int l = labels[node];
                midx[pos] = node;
                mlab[pos] = l;
                atomicAdd(&sN[l], 1);
                pos++;
            }
        }
        __syncthreads();
        if (t < NC) ((int*)acc)[49 + t] = sN[t];
        if (t == 255) ((int*)acc)[60] = cnts[255];   // M
    } else {
        int p = blockIdx.x * 256 + t;
        int l = labels[p];
        const float* pr = preds + p * NC;
        float x[NC];
        #pragma unroll
        for (int c = 0; c < NC; c++) x[c] = pr[c];
        float mx = x[0];
        #pragma unroll
        for (int c = 1; c < NC; c++) mx = fmaxf(mx, x[c]);
        float s = 0.f;
        #pragma unroll
        for (int c = 0; c < NC; c++) s += __expf(x[c] - mx);
        float lse = mx + logf(s);
        float dp = x[l];
        diagP[p] = dp;

        __shared__ float red[256];
        red[t] = lse - dp;
        __syncthreads();
        for (int st = 128; st > 0; st >>= 1) {
            if (t < st) red[t] += red[t + st];
            __syncthreads();
        }
        if (t == 0) acc[61 + blockIdx.x] = red[0];   // pure write, no atomic
    }
}

// Pair kernel over compacted masked nodes. 64x64 tile, 4x4 per thread.
// K split in 2 halves of 16 x 16B chunks => LDS ~36KB => 4 blocks/CU.
// Swizzle pos = c ^ ((row>>2)&7): p-reads conflict-free, q-reads 2-way (free).
__launch_bounds__(256, 4)
__global__ void k_pairs(const unsigned long long* __restrict__ bits,
                        const float* __restrict__ preds,
                        const int* __restrict__ deg,
                        const float* __restrict__ diagP,
                        const int* __restrict__ selfq,
                        const int* __restrict__ midx,
                        const int* __restrict__ mlab,
                        const int* __restrict__ Mptr,
                        float* __restrict__ T,
                        unsigned int* __restrict__ g_masks) {
    __shared__ ulonglong2 lp[64 * 16];
    __shared__ ulonglong2 lq[64 * 16];
    __shared__ float predsQ[NC * 64];   // transposed [c][r]: E-reads bank-conflict-free
    __shared__ float diagPp[64];
    __shared__ int labP[64], labQ[64], degP[64], origQ[64], sSelf[64];
    __shared__ float T_lds[49];
    __shared__ unsigned int s_m[4];

    int M = Mptr[0];
    int p0 = blockIdx.y * 64, q0 = blockIdx.x * 64;
    if (p0 >= M || q0 >= M) return;

    int t = threadIdx.x;
    if (t < 49) T_lds[t] = 0.f;
    if (t >= 49 && t < 53) s_m[t - 49] = 0u;
    if (t < 64) {
        int pi = midx[p0 + t], qi = midx[q0 + t];
        diagPp[t] = diagP[pi];
        degP[t] = deg[pi];
        labP[t] = mlab[p0 + t];
        labQ[t] = mlab[q0 + t];
        origQ[t] = qi;
        sSelf[t] = selfq[qi];
    }
    for (int idx = t; idx < NC * 64; idx += 256) {
        int c = idx >> 6, r = idx & 63;
        predsQ[idx] = preds[midx[q0 + r] * NC + c];
    }

    int tx = t & 15, ty = t >> 4;
    int cnt[4][4] = {};
    unsigned int pqbits = 0;   // bit (i*4+j) = adj[p_i, q_j]

    for (int h = 0; h < 2; h++) {
        __syncthreads();   // h=0: covers meta staging; h=1: protects prev-half reads
        #pragma unroll
        for (int i2 = 0; i2 < 4; i2++) {
            int idx = t + 256 * i2;            // 0..1023 (64 rows x 16 chunks)
            int row = idx >> 4, lc = idx & 15;
            int sc = lc ^ ((row >> 2) & 7);
            lp[row * 16 + sc] = *(const ulonglong2*)&bits[(size_t)midx[p0 + row] * 64 + 32 * h + 2 * lc];
            lq[row * 16 + sc] = *(const ulonglong2*)&bits[(size_t)midx[q0 + row] * 64 + 32 * h + 2 * lc];
        }
        __syncthreads();

        const ulonglong2* Ap = lp + ty * 64;   // row 4ty+i at offset ty*64 + i*16
        const ulonglong2* Bp = lq + tx * 64;
        #pragma unroll 4
        for (int c = 0; c < 16; c++) {
            int sa = c ^ (ty & 7);
            int sb = c ^ (tx & 7);
            ulonglong2 a[4], b[4];
            #pragma unroll
            for (int i = 0; i < 4; i++) a[i] = Ap[i * 16 + sa];
            #pragma unroll
            for (int j = 0; j < 4; j++) b[j] = Bp[j * 16 + sb];
            #pragma unroll
            for (int i = 0; i < 4; i++)
                #pragma unroll
                for (int j = 0; j < 4; j++)
                    cnt[i][j] += __popcll(a[i].x & b[j].x) + __popcll(a[i].y & b[j].y);
        }

        // extract adj[p,q] for pairs whose q-bit chunk lives in this half
        #pragma unroll
        for (int j = 0; j < 4; j++) {
            int qorig = origQ[4 * tx + j];
            int qc = qorig >> 7;               // global 16B chunk 0..31
            if ((qc >> 4) == h) {
                int lc = qc & 15;
                int qh = (qorig >> 6) & 1;
                int sh = qorig & 63;
                #pragma unroll
                for (int i = 0; i < 4; i++) {
                    ulonglong2 cp = lp[(4 * ty + i) * 16 + (lc ^ (ty & 7))];
                    unsigned long long w = qh ? cp.y : cp.x;
                    pqbits |= ((unsigned int)((w >> sh) & 1ull)) << (i * 4 + j);
                }
            }
        }
    }

    unsigned long long lsub = 0ull, linter = 0ull;
    #pragma unroll
    for (int i = 0; i < 4; i++) {
        int pl = 4 * ty + i;
        bool pOK = (p0 + pl) < M;
        int lp_ = labP[pl], dgp = degP[pl];
        float dPp = diagPp[pl];
        #pragma unroll
        for (int j = 0; j < 4; j++) {
            int ql = 4 * tx + j;
            if (!pOK || (q0 + ql) >= M) continue;
            int inter = cnt[i][j];
            int bit_pq = (pqbits >> (i * 4 + j)) & 1;
            int sub = dgp - inter - (bit_pq & (sSelf[ql] ^ 1));
            int lq_ = labQ[ql];
            int bidx = lp_ * 7 + lq_;
            if (sub > 0)   lsub   |= 1ull << bidx;
            if (inter > 0) linter |= 1ull << bidx;
            if (lp_ != lq_) {
                float arg = (1.f + SIG1 * (float)sub) / (1.f + SIG1 * (float)inter);
                float v = 1.f / (1.f + __expf(arg));            // 1 - sigmoid(arg)
                float E = __expf(predsQ[lp_ * 64 + ql] - dPp);  // exp(G - diagP)
                atomicAdd(&T_lds[bidx], E * v);
            }
        }
    }
    atomicOr(&s_m[0], (unsigned int)(lsub & 0xffffffffull));
    atomicOr(&s_m[1], (unsigned int)(lsub >> 32));
    atomicOr(&s_m[2], (unsigned int)(linter & 0xffffffffull));
    atomicOr(&s_m[3], (unsigned int)(linter >> 32));
    __syncthreads();

    if (t < 49) { float v = T_lds[t]; if (v != 0.f) atomicAdd(&T[t], v); }
    if (t >= 64 && t < 68) { unsigned int m = s_m[t - 64]; if (m) atomicOr(&g_masks[t - 64], m); }
}

__global__ void k_final(const float* __restrict__ acc, float* __restrict__ out) {
    if (threadIdx.x == 0 && blockIdx.x == 0) {
        const float* T = acc;
        const int* Ncnt = (const int*)(acc + 49);
        const unsigned int* m = (const unsigned int*)(acc + 56);
        float ce = 0.f;
        for (int b = 0; b < 16; b++) ce += acc[61 + b];
        ce /= (float)NN;
        unsigned long long sub  = (unsigned long long)m[0] | ((unsigned long long)m[1] << 32);
        unsigned long long intr = (unsigned long long)m[2] | ((unsigned long long)m[3] << 32);
        unsigned long long hb = sub & intr;
        float invN[NC];
        #pragma unroll
        for (int c = 0; c < NC; c++) { int n = Ncnt[c]; invN[c] = (n > 0) ? 1.f / (float)n : 0.f; }
        float lp = 0.f;
        for (int c1 = 0; c1 < NC; c1++)
            for (int c2 = 0; c2 < NC; c2++) {
                int b = c1 * 7 + c2;
                if ((hb >> b) & 1ull) lp += invN[c1] * invN[c2] * T[b];
            }
        out[0] = ce + PER_C * lp;
    }
}

extern "C" void kernel_launch(void* const* d_in, const int* in_sizes, int n_in,
                              void* d_out, int out_size, void* d_ws, size_t ws_size,
                              hipStream_t stream) {
    const float* preds  = (const float*)d_in[0];
    const int*   labels = (const int*)d_in[1];
    const int*   mask   = (const int*)d_in[2];
    const int*   adj    = (const int*)d_in[3];
    float* out = (float*)d_out;

    char* ws = (char*)d_ws;
    unsigned long long* bits = (unsigned long long*)(ws + BITS_OFF);
    int*   deg   = (int*)(ws + DEG_OFF);
    float* diagP = (float*)(ws + DIAGP_OFF);
    int*   selfq = (int*)(ws + SELF_OFF);
    int*   midx  = (int*)(ws + MIDX_OFF);
    int*   mlab  = (int*)(ws + MLAB_OFF);
    float* acc   = (float*)(ws + ACC_OFF);
    float* T       = acc;
    const int* Mptr = (const int*)(acc + 60);
    unsigned int* g_masks = (unsigned int*)(acc + 56);

    k_build<<<1024, 256, 0, stream>>>(adj, bits, deg, selfq);
    k_prep2<<<17, 256, 0, stream>>>(preds, labels, mask, diagP, midx, mlab, acc);
    dim3 grid(64, 64);
    k_pairs<<<grid, 256, 0, stream>>>(bits, preds, deg, diagP, selfq, midx, mlab, Mptr, T, g_masks);
    k_final<<<1, 64, 0, stream>>>(acc, out);
}